// Round 4
// baseline (58.839 us; speedup 1.0000x reference)
//
#include <hip/hip_runtime.h>

// Problem constants (from reference): B=8, N=64, I=128, H=1024
#define BB 8
#define NN 64
#define II 128
#define HH 1024
#define TOTAL_OUT (BB * NN * II)   // 65536

// Kernel 1 (round-2 proven version): v[b][j] = sum_k W[j][k] * hidden[b][k]
// One wave per j (1024 waves). W row read coalesced via float4; hidden is
// 32 KB, L2-hot.
__global__ void compute_v_kernel(const float* __restrict__ W,
                                 const float* __restrict__ hidden,
                                 float* __restrict__ v) {
    int wave = (blockIdx.x * blockDim.x + threadIdx.x) >> 6;
    int lane = threadIdx.x & 63;
    if (wave >= HH) return;
    int j = wave;

    const float4* Wrow = reinterpret_cast<const float4*>(W + (size_t)j * HH);
    const float4* Hv   = reinterpret_cast<const float4*>(hidden);

    float acc[BB];
#pragma unroll
    for (int b = 0; b < BB; ++b) acc[b] = 0.f;

#pragma unroll
    for (int it = 0; it < HH / 256; ++it) {        // 4 iterations
        float4 w4 = Wrow[it * 64 + lane];
#pragma unroll
        for (int b = 0; b < BB; ++b) {
            float4 h4 = Hv[b * (HH / 4) + it * 64 + lane];
            acc[b] += w4.x * h4.x + w4.y * h4.y + w4.z * h4.z + w4.w * h4.w;
        }
    }

#pragma unroll
    for (int b = 0; b < BB; ++b) {
        float a = acc[b];
#pragma unroll
        for (int off = 32; off > 0; off >>= 1) a += __shfl_xor(a, off, 64);
        if (lane == 0) v[b * HH + j] = a;
    }
}

// Kernel 2: out[o] = dot(enc[o, :], v[b, :]) + bias.
// One wave per 8 consecutive rows (all share b). v[b,:] is loaded ONCE into
// 4 float4 registers per lane; the row loop then streams pure enc traffic —
// 4 independent float4 loads per row, no L2 v-loads in the hot loop.
__global__ void bilinear_out_kernel(const float* __restrict__ enc,
                                    const float* __restrict__ v,
                                    const float* __restrict__ bias,
                                    float* __restrict__ out) {
    int wave = (blockIdx.x * blockDim.x + threadIdx.x) >> 6;
    int lane = threadIdx.x & 63;
    int o0 = wave * 8;
    if (o0 >= TOTAL_OUT) return;
    int b = o0 >> 13;                               // N*I = 8192 rows per b; 8 | 8192

    const float4* e0 = reinterpret_cast<const float4*>(enc) + (size_t)o0 * (HH / 4);
    const float4* vr = reinterpret_cast<const float4*>(v) + (size_t)b * (HH / 4);

    // Whole v row in registers: lane covers elements {lane, 64+lane, 128+lane, 192+lane} (x4)
    float4 vv0 = vr[lane];
    float4 vv1 = vr[64 + lane];
    float4 vv2 = vr[128 + lane];
    float4 vv3 = vr[192 + lane];

    float accs[8];
#pragma unroll
    for (int r = 0; r < 8; ++r) {
        const float4* er = e0 + r * (HH / 4);
        float4 x0 = er[lane];
        float4 x1 = er[64 + lane];
        float4 x2 = er[128 + lane];
        float4 x3 = er[192 + lane];
        float a;
        a  = x0.x * vv0.x + x0.y * vv0.y + x0.z * vv0.z + x0.w * vv0.w;
        a += x1.x * vv1.x + x1.y * vv1.y + x1.z * vv1.z + x1.w * vv1.w;
        a += x2.x * vv2.x + x2.y * vv2.y + x2.z * vv2.z + x2.w * vv2.w;
        a += x3.x * vv3.x + x3.y * vv3.y + x3.z * vv3.z + x3.w * vv3.w;
        accs[r] = a;
    }

#pragma unroll
    for (int r = 0; r < 8; ++r) {
#pragma unroll
        for (int off = 32; off > 0; off >>= 1)
            accs[r] += __shfl_xor(accs[r], off, 64);
    }

    if (lane == 0) {
        float bb = bias[0];
        float4 r0 = make_float4(accs[0] + bb, accs[1] + bb, accs[2] + bb, accs[3] + bb);
        float4 r1 = make_float4(accs[4] + bb, accs[5] + bb, accs[6] + bb, accs[7] + bb);
        *reinterpret_cast<float4*>(out + o0)     = r0;
        *reinterpret_cast<float4*>(out + o0 + 4) = r1;
    }
}

extern "C" void kernel_launch(void* const* d_in, const int* in_sizes, int n_in,
                              void* d_out, int out_size, void* d_ws, size_t ws_size,
                              hipStream_t stream) {
    const float* hidden = (const float*)d_in[0];   // [B, H]
    const float* enc    = (const float*)d_in[1];   // [B, N, I, H]
    // d_in[2] = input_lengths (unused by the math)
    const float* W      = (const float*)d_in[3];   // [H, H]
    const float* bias   = (const float*)d_in[4];   // [1]
    float* out = (float*)d_out;                    // [B, N, I] f32
    float* v   = (float*)d_ws;                     // [B, H] scratch = 32 KB

    // Kernel 1: 1024 waves -> 256 blocks x 256 threads
    compute_v_kernel<<<(HH * 64) / 256, 256, 0, stream>>>(W, hidden, v);

    // Kernel 2: 8192 waves (8 rows each) -> 2048 blocks x 256 threads
    bilinear_out_kernel<<<(TOTAL_OUT / 8 * 64) / 256, 256, 0, stream>>>(enc, v, bias, out);
}

// Round 6
// 47.686 us; speedup vs baseline: 1.2339x; 1.2339x over previous
//
#include <hip/hip_runtime.h>

// Problem constants (from reference): B=8, N=64, I=128, H=1024
#define BB 8
#define NN 64
#define II 128
#define HH 1024
#define TOTAL_OUT (BB * NN * II)   // 65536

// Kernel 1: v[b][j] = sum_k W[j][k] * hidden[b][k]
// One 256-thread block per j: whole W row (4 KB) in a SINGLE round of 256
// independent float4 loads (one HBM latency exposure), hidden L2-hot.
// Wave shuffle-reduce + tiny LDS cross-wave combine.
__global__ void compute_v_kernel(const float* __restrict__ W,
                                 const float* __restrict__ hidden,
                                 float* __restrict__ v) {
    int j    = blockIdx.x;          // 0..1023
    int t    = threadIdx.x;         // 0..255
    int lane = t & 63;
    int w    = t >> 6;              // wave 0..3

    const float4* Wrow = reinterpret_cast<const float4*>(W + (size_t)j * HH);
    const float4* Hv   = reinterpret_cast<const float4*>(hidden);

    float4 w4 = Wrow[t];            // 256 float4 = full row
    float acc[BB];
#pragma unroll
    for (int b = 0; b < BB; ++b) {
        float4 h4 = Hv[b * (HH / 4) + t];
        acc[b] = w4.x * h4.x + w4.y * h4.y + w4.z * h4.z + w4.w * h4.w;
    }

#pragma unroll
    for (int b = 0; b < BB; ++b) {
#pragma unroll
        for (int off = 32; off > 0; off >>= 1)
            acc[b] += __shfl_xor(acc[b], off, 64);
    }

    __shared__ float part[4][BB];
    if (lane == 0) {
#pragma unroll
        for (int b = 0; b < BB; ++b) part[w][b] = acc[b];
    }
    __syncthreads();
    if (t < BB) {
        v[t * HH + j] = part[0][t] + part[1][t] + part[2][t] + part[3][t];
    }
}

// Kernel 2 (R2 proven version, unchanged): out[o] = dot(enc[o,:], v[b,:]) + bias.
// One wave per TWO consecutive output rows.
__global__ void bilinear_out_kernel(const float* __restrict__ enc,
                                    const float* __restrict__ v,
                                    const float* __restrict__ bias,
                                    float* __restrict__ out) {
    int wave = (blockIdx.x * blockDim.x + threadIdx.x) >> 6;
    int lane = threadIdx.x & 63;
    int o0 = wave * 2;
    if (o0 >= TOTAL_OUT) return;
    int b = o0 >> 13;                               // N*I = 8192 = 2^13

    const float4* e0 = reinterpret_cast<const float4*>(enc) + (size_t)o0 * (HH / 4);
    const float4* e1 = e0 + (HH / 4);
    const float4* vr = reinterpret_cast<const float4*>(v) + (size_t)b * (HH / 4);

    float a0 = 0.f, a1 = 0.f;
#pragma unroll
    for (int it = 0; it < HH / 256; ++it) {         // 4 iterations
        float4 x0 = e0[it * 64 + lane];
        float4 x1 = e1[it * 64 + lane];
        float4 vv = vr[it * 64 + lane];
        a0 += x0.x * vv.x + x0.y * vv.y + x0.z * vv.z + x0.w * vv.w;
        a1 += x1.x * vv.x + x1.y * vv.y + x1.z * vv.z + x1.w * vv.w;
    }

#pragma unroll
    for (int off = 32; off > 0; off >>= 1) {
        a0 += __shfl_xor(a0, off, 64);
        a1 += __shfl_xor(a1, off, 64);
    }
    if (lane == 0) {
        float bb = bias[0];
        out[o0]     = a0 + bb;
        out[o0 + 1] = a1 + bb;
    }
}

extern "C" void kernel_launch(void* const* d_in, const int* in_sizes, int n_in,
                              void* d_out, int out_size, void* d_ws, size_t ws_size,
                              hipStream_t stream) {
    const float* hidden = (const float*)d_in[0];   // [B, H]
    const float* enc    = (const float*)d_in[1];   // [B, N, I, H]
    // d_in[2] = input_lengths (unused by the math)
    const float* W      = (const float*)d_in[3];   // [H, H]
    const float* bias   = (const float*)d_in[4];   // [1]
    float* out = (float*)d_out;                    // [B, N, I] f32
    float* v   = (float*)d_ws;                     // [B, H] scratch = 32 KB

    // Kernel 1: one block per j -> 1024 blocks x 256 threads
    compute_v_kernel<<<HH, 256, 0, stream>>>(W, hidden, v);

    // Kernel 2: 32768 waves (2 rows each) -> 8192 blocks x 256 threads
    bilinear_out_kernel<<<(TOTAL_OUT / 2 * 64) / 256, 256, 0, stream>>>(enc, v, bias, out);
}